// Round 18
// baseline (163.588 us; speedup 1.0000x reference)
//
#include <hip/hip_runtime.h>
#include <hip/hip_bf16.h>

#define NN 4096

typedef unsigned short u16;
typedef __attribute__((ext_vector_type(8))) short bf16x8;
typedef __attribute__((ext_vector_type(4))) float f32x4;

// fp32 -> bf16 round-to-nearest-even
static __device__ __forceinline__ u16 f2bf(float x) {
  unsigned u = __float_as_uint(x);
  u += 0x7fff + ((u >> 16) & 1);
  return (u16)(u >> 16);
}
static __device__ __forceinline__ float bf2f(u16 h) {
  return __uint_as_float((unsigned)h << 16);
}

// async global->LDS, 16B per lane; LDS dest = wave-uniform base + lane*16
static __device__ __forceinline__ void gload_lds16(const void* g, void* l) {
  __builtin_amdgcn_global_load_lds(
      (const __attribute__((address_space(1))) void*)g,
      (__attribute__((address_space(3))) void*)l, 16, 0, 0);
}

// Balanced partition of 3264 global K64-steps over 256 blocks:
// blocks 0..191 get 13 steps, 192..255 get 12  (192*13 + 64*12 = 3264).
static __device__ __forceinline__ int stepStart(int b) {
  return b < 192 ? 13 * b : 2496 + 12 * (b - 192);
}
static __device__ __forceinline__ int bOf(int s) {
  return s < 2496 ? s / 13 : 192 + (s - 2496) / 12;
}

// ---------------------------------------------------------------------------
// Pass 1 (fused, grid 3200): R16 structure + R17 ILP batching.
// ---------------------------------------------------------------------------
__global__ __launch_bounds__(256) void convert_fused(
    const float* __restrict__ A, const float* __restrict__ B,
    u16* __restrict__ Ab, u16* __restrict__ Bt) {
  __shared__ float t[64][65];
  const int blk = blockIdx.x;
  const int tid = threadIdx.x;

  if (blk < 1024) {  // ---- A path: 128x128 block (bi,kb) ----
    const int kb = blk & 31, bi = blk >> 5;
    const int rr = tid >> 5;
    if (kb > bi) {
      if (kb == bi + 1 && !(bi & 1)) {  // super-diagonal Ab: real zeros
        const ushort4 zz = {0, 0, 0, 0};
        const int c4b = (tid & 31) * 4;
#pragma unroll
        for (int p = 0; p < 16; ++p)
          *(ushort4*)&Ab[(long)(bi * 128 + p * 8 + rr) * NN + kb * 128 + c4b] =
              zz;
      }
      return;
    }
    const int c4 = (tid & 31) * 4;
    const bool diag = (kb == bi);
#pragma unroll
    for (int h = 0; h < 2; ++h) {
      float4 v[8];
#pragma unroll
      for (int p = 0; p < 8; ++p) {  // 8 loads in flight (ILP)
        const int row = (h * 8 + p) * 8 + rr;
        v[p] = *(const float4*)&A[(long)(bi * 128 + row) * NN + kb * 128 + c4];
      }
#pragma unroll
      for (int p = 0; p < 8; ++p) {
        const int row = (h * 8 + p) * 8 + rr;
        ushort4 o;
        if (diag) {
          const int i = bi * 128 + row, k = kb * 128 + c4;
          o.x = (k + 0 <= i) ? f2bf(v[p].x) : (u16)0;
          o.y = (k + 1 <= i) ? f2bf(v[p].y) : (u16)0;
          o.z = (k + 2 <= i) ? f2bf(v[p].z) : (u16)0;
          o.w = (k + 3 <= i) ? f2bf(v[p].w) : (u16)0;
        } else {
          o.x = f2bf(v[p].x); o.y = f2bf(v[p].y);
          o.z = f2bf(v[p].z); o.w = f2bf(v[p].w);
        }
        *(ushort4*)&Ab[(long)(bi * 128 + row) * NN + kb * 128 + c4] = o;
      }
    }
    return;
  }

  if (blk >= 3136) {  // ---- sub-diagonal Bt zero blocks ----
    const int idx = blk - 3136;  // 0..63
    const int q = idx >> 2;
    const int n0 = (2 * (2 * q + 1) + (idx & 1)) * 64;
    const int k0 = (2 * (2 * q) + ((idx >> 1) & 1)) * 64;
    const int n = tid >> 3;
    const int kc = (tid & 7) * 8;
    const uint4 z = {0u, 0u, 0u, 0u};
#pragma unroll
    for (int p = 0; p < 2; ++p)
      *(uint4*)&Bt[(long)(n0 + n + p * 32) * NN + k0 + kc] = z;
    return;
  }

  // ---- B path: pair-decoded 64x64 transpose tile ----
  const int t4 = blk - 1024;  // 0..2111
  int prem = t4 >> 2, N = 0;
  while (prem >= 32 - N) { prem -= 32 - N; ++N; }
  const int K = N + prem;  // N <= K
  const int sub = t4 & 3;
  const int n0 = (2 * N + (sub & 1)) * 64;
  const int k0 = (2 * K + (sub >> 1)) * 64;

  if (n0 > k0 + 63) {  // fully above diagonal -> zeros
    const int n = tid >> 3;
    const int kc = (tid & 7) * 8;
    const uint4 z = {0u, 0u, 0u, 0u};
#pragma unroll
    for (int p = 0; p < 2; ++p)
      *(uint4*)&Bt[(long)(n0 + n + p * 32) * NN + k0 + kc] = z;
    return;
  }

  float4 w[4];
#pragma unroll
  for (int p = 0; p < 4; ++p) {  // 4 loads in flight (ILP)
    const int r = (tid >> 4) + p * 16;
    w[p] = *(const float4*)&B[(long)(k0 + r) * NN + n0 + (tid & 15) * 4];
  }
#pragma unroll
  for (int p = 0; p < 4; ++p) {
    const int r = (tid >> 4) + p * 16;
    const int c = (tid & 15) * 4;
    const int kg = k0 + r;
    t[r][c + 0] = (n0 + c + 0 <= kg) ? w[p].x : 0.f;
    t[r][c + 1] = (n0 + c + 1 <= kg) ? w[p].y : 0.f;
    t[r][c + 2] = (n0 + c + 2 <= kg) ? w[p].z : 0.f;
    t[r][c + 3] = (n0 + c + 3 <= kg) ? w[p].w : 0.f;
  }
  __syncthreads();

#pragma unroll
  for (int p = 0; p < 2; ++p) {
    const int n = (tid >> 3) + p * 32;
    const int kc = (tid & 7) * 8;
    union { u16 h[8]; uint4 v; } pk;
#pragma unroll
    for (int j = 0; j < 8; ++j) pk.h[j] = f2bf(t[kc + j][n]);
    *(uint4*)&Bt[(long)(n0 + n) * NN + k0 + kc] = pk.v;
  }
}

// ---------------------------------------------------------------------------
// One segment of the gemm: the PROVEN R16 inner body (spread staging,
// 1 barrier/step, lgkmcnt(4) phase pipeline, T2 swizzle, setprio).
// Owner segments (k0s==0) write C (diag-masked); continuations write bf16
// slab P[myslab].
// ---------------------------------------------------------------------------
static __device__ __forceinline__ void run_segment(
    const u16* __restrict__ Ab, const u16* __restrict__ Bt,
    float* __restrict__ C, u16* __restrict__ P, u16* AsB, u16* BsB,
    int bi, int bj, int k0s, int nk, int myslab, int lane, int wid, int wm,
    int wn, int sm, int sks, int rsel) {
  const int rA = bi * 256;
  const int rB = bj * 256;
  const long kbase = (long)bj * 256 + (long)k0s * 64;

  f32x4 acc[8][4];
#pragma unroll
  for (int i = 0; i < 8; ++i)
#pragma unroll
    for (int j = 0; j < 4; ++j) acc[i][j] = (f32x4){0.f, 0.f, 0.f, 0.f};

#define STAGE_PART(kt, b, c)                                               \
  do {                                                                     \
    const long k0 = kbase + (long)(kt)*64;                                 \
    const int ch = wid * 4 + (c);                                          \
    gload_lds16(Ab + ((long)(rA + ch * 8 + sm) * NN + k0 + sks),           \
                AsB + (b)*16384 + ch * 512);                               \
    gload_lds16(Bt + ((long)(rB + ch * 8 + sm) * NN + k0 + sks),           \
                BsB + (b)*16384 + ch * 512);                               \
  } while (0)

#pragma unroll
  for (int c = 0; c < 4; ++c) STAGE_PART(0, 0, c);

  for (int kt = 0; kt < nk; ++kt) {
    const int cur = kt & 1;
    asm volatile("s_waitcnt vmcnt(0)" ::: "memory");  // own stage landed
    __builtin_amdgcn_s_barrier();                     // all waves' stage done
    __builtin_amdgcn_sched_barrier(0);                // no read hoists above

    const u16* As = AsB + cur * 16384;
    const u16* Bs = BsB + cur * 16384;
    const bool pf = (kt + 1 < nk);

    bf16x8 bb[4][2];
#pragma unroll
    for (int n4 = 0; n4 < 4; ++n4)
#pragma unroll
      for (int kk = 0; kk < 2; ++kk) {
        const int fr = wn * 64 + n4 * 16 + (lane & 15);
        const int slot = ((kk * 4 + (lane >> 4)) ^ rsel) * 8;
        bb[n4][kk] = *(const bf16x8*)&Bs[fr * 64 + slot];
      }
    bf16x8 aa[2][2][2];  // [phase&1][mm][kk]
#pragma unroll
    for (int mm = 0; mm < 2; ++mm)
#pragma unroll
      for (int kk = 0; kk < 2; ++kk) {
        const int fr = wm * 128 + mm * 16 + (lane & 15);
        const int slot = ((kk * 4 + (lane >> 4)) ^ rsel) * 8;
        aa[0][mm][kk] = *(const bf16x8*)&As[fr * 64 + slot];
      }

#pragma unroll
    for (int p = 0; p < 4; ++p) {
      if (pf) STAGE_PART(kt + 1, cur ^ 1, p);  // 2 global loads interleaved
      if (p < 3) {  // prefetch next phase's A fragments
#pragma unroll
        for (int mm = 0; mm < 2; ++mm)
#pragma unroll
          for (int kk = 0; kk < 2; ++kk) {
            const int fr = wm * 128 + (2 * (p + 1) + mm) * 16 + (lane & 15);
            const int slot = ((kk * 4 + (lane >> 4)) ^ rsel) * 8;
            aa[(p + 1) & 1][mm][kk] = *(const bf16x8*)&As[fr * 64 + slot];
          }
        asm volatile("s_waitcnt lgkmcnt(4)" ::: "memory");  // cur frags done
      } else {
        asm volatile("s_waitcnt lgkmcnt(0)" ::: "memory");
      }
      __builtin_amdgcn_sched_barrier(0);  // rule #18: no MFMA hoist past wait
      __builtin_amdgcn_s_setprio(1);
#pragma unroll
      for (int kk = 0; kk < 2; ++kk)
#pragma unroll
        for (int mm = 0; mm < 2; ++mm)
#pragma unroll
          for (int n4 = 0; n4 < 4; ++n4)
            acc[2 * p + mm][n4] = __builtin_amdgcn_mfma_f32_16x16x32_bf16(
                aa[p & 1][mm][kk], bb[n4][kk], acc[2 * p + mm][n4], 0, 0, 0);
      __builtin_amdgcn_s_setprio(0);
    }
  }
#undef STAGE_PART

  const int lrow = wm * 128 + (lane >> 4) * 4;
  const int lcol = wn * 64 + (lane & 15);
  if (k0s == 0) {  // owner
    const bool diag = (bi == bj);
#pragma unroll
    for (int m4 = 0; m4 < 8; ++m4)
#pragma unroll
      for (int n4 = 0; n4 < 4; ++n4)
#pragma unroll
        for (int r = 0; r < 4; ++r) {
          const int gi = rA + lrow + m4 * 16 + r;
          const int gj = rB + lcol + n4 * 16;
          float v = acc[m4][n4][r];
          if (diag && gj > gi) v = 0.f;
          C[(long)gi * NN + gj] = v;
        }
  } else {  // continuation -> bf16 slab
    u16* slab = P + (long)myslab * 65536;
#pragma unroll
    for (int m4 = 0; m4 < 8; ++m4)
#pragma unroll
      for (int n4 = 0; n4 < 4; ++n4)
#pragma unroll
        for (int r = 0; r < 4; ++r)
          slab[(lrow + m4 * 16 + r) * 256 + lcol + n4 * 16] =
              f2bf(acc[m4][n4][r]);
  }
}

// ---------------------------------------------------------------------------
// Pass 2: BALANCED 256-block gemm. Tiles (bi=15..0, bj=0..bi) laid out in a
// global K64-step sequence [0,3264); block b owns [stepStart(b),
// stepStart(b+1)) = 12-13 steps = the ideal per-CU share (3264/256=12.75).
// Decode is pure SALU, UP FRONT (<=4 uniform segment descriptors as named
// scalars) -- the R14 spill came from keeping walk state live inside the
// acc-live loop; here each segment body is codegen-identical to R16's
// proven single-item kernel. Blocks >= 256 zero strictly-upper C tiles.
// ---------------------------------------------------------------------------
__global__ __launch_bounds__(512, 2) void gemm_tril(
    const u16* __restrict__ Ab, const u16* __restrict__ Bt,
    float* __restrict__ C, u16* __restrict__ P) {
  extern __shared__ u16 lds[];  // [2][16384] A | [2][16384] B = 128 KB
  u16* AsB = lds;
  u16* BsB = lds + 32768;

  const int tid = threadIdx.x;

  if ((int)blockIdx.x >= 256) {  // ---- zero a strictly-upper 256-tile ----
    int zi = blockIdx.x - 256;   // 0..119
    int bi = 0;
    for (; bi < 15; ++bi) {
      const int u = 15 - bi;
      if (zi < u) break;
      zi -= u;
    }
    const int bj = bi + 1 + zi;
    const float4 z = {0.f, 0.f, 0.f, 0.f};
#pragma unroll
    for (int p = 0; p < 32; ++p) {
      const int idx = p * 512 + tid;
      const int row = idx >> 6;
      const int col = (idx & 63) * 4;
      *(float4*)&C[(long)(bi * 256 + row) * NN + bj * 256 + col] = z;
    }
    return;
  }

  // ---- SALU decode: slice -> up to 4 segments (all uniform scalars) ----
  int s0 = stepStart(blockIdx.x);
  const int send = stepStart(blockIdx.x + 1);

  int S = 0, bi = 15;
  for (int s = 0; s < 16; ++s) {
    bi = 15 - s;
    const int rl = 2 * (bi + 1) * (bi + 2);  // steps in 256-row bi
    if (s0 < S + rl) break;
    S += rl;
  }
  int bj = 0;
  while (s0 >= S + 4 * (bi - bj + 1)) {
    S += 4 * (bi - bj + 1);
    ++bj;
  }

  int gBi[4], gBj[4], gK0[4], gNk[4];
  int nseg = 0;
#pragma unroll
  for (int sg = 0; sg < 4; ++sg) {
    if (s0 < send) {
      const int L = 4 * (bi - bj + 1);
      const int k0s = s0 - S;
      const int nk = min(L - k0s, send - s0);
      gBi[sg] = bi; gBj[sg] = bj; gK0[sg] = k0s; gNk[sg] = nk;
      ++nseg;
      s0 += nk;
      S += L;
      if (++bj > bi) { --bi; bj = 0; }
    } else {
      gBi[sg] = 0; gBj[sg] = 0; gK0[sg] = 0; gNk[sg] = 0;
    }
  }

  const int lane = tid & 63;
  const int wid = tid >> 6;
  const int wm = wid >> 2;
  const int wn = wid & 3;
  const int sm = lane >> 3;
  const int sks = ((lane & 7) ^ sm) * 8;
  const int rsel = lane & 7;

#pragma unroll
  for (int sg = 0; sg < 4; ++sg) {
    if (sg < nseg)
      run_segment(Ab, Bt, C, P, AsB, BsB, gBi[sg], gBj[sg], gK0[sg], gNk[sg],
                  blockIdx.x, lane, wid, wm, wn, sm, sks, rsel);
  }
}

// ---------------------------------------------------------------------------
// Pass 3: per split tile, add continuation slabs P[b0+1..blast] into C.
// Grid = 136 tiles x 4 row-stripes.
// ---------------------------------------------------------------------------
__global__ __launch_bounds__(256) void reduce_partials(
    float* __restrict__ C, const u16* __restrict__ P) {
  const int T = blockIdx.x >> 2;
  const int stripe = blockIdx.x & 3;

  // decode tile T (order: bi=15..0, bj=0..bi) -> (bi, bj, step prefix S)
  int rem = T, bi = 15, S = 0;
  for (int s = 0; s < 16; ++s) {
    bi = 15 - s;
    if (rem <= bi) break;
    rem -= bi + 1;
    S += 2 * (bi + 1) * (bi + 2);
  }
  const int bj = rem;
  for (int j = 0; j < bj; ++j) S += 4 * (bi - j + 1);
  const int L = 4 * (bi - bj + 1);

  const int b0 = bOf(S);
  const int blast = bOf(S + L - 1);
  if (blast == b0) return;  // tile not split across blocks

  const int tid = threadIdx.x;
#pragma unroll
  for (int p = 0; p < 16; ++p) {
    const int idx = p * 256 + tid;  // 4096 float4 per 64-row stripe
    const int row = stripe * 64 + (idx >> 6);
    const int col = (idx & 63) * 4;
    const long coff = (long)(bi * 256 + row) * NN + bj * 256 + col;
    float4 acc = *(const float4*)&C[coff];
    for (int e = b0 + 1; e <= blast; ++e) {
      const ushort4 q = *(const ushort4*)&P[(long)e * 65536 + row * 256 + col];
      acc.x += bf2f(q.x); acc.y += bf2f(q.y);
      acc.z += bf2f(q.z); acc.w += bf2f(q.w);
    }
    *(float4*)&C[coff] = acc;
  }
}

// ---------------------------------------------------------------------------
// Fallback (ws too small): naive fp32.
// ---------------------------------------------------------------------------
__global__ void naive_tril(const float* __restrict__ A,
                           const float* __restrict__ B, float* __restrict__ C) {
  const int j = blockIdx.x * 256 + threadIdx.x;
  const int i = blockIdx.y;
  float s = 0.f;
  for (int k = j; k <= i; ++k) s += A[(long)i * NN + k] * B[(long)k * NN + j];
  C[(long)i * NN + j] = s;
}

extern "C" void kernel_launch(void* const* d_in, const int* in_sizes, int n_in,
                              void* d_out, int out_size, void* d_ws,
                              size_t ws_size, hipStream_t stream) {
  const float* A = (const float*)d_in[0];
  const float* B = (const float*)d_in[1];
  float* C = (float*)d_out;

  const size_t opbytes = (size_t)2 * NN * NN * sizeof(u16);  // 64 MB
  const size_t need = opbytes + (size_t)256 * 131072;        // +32 MB slabs

  if (ws_size < need) {  // ws >= 107.5 MB proven (R13); safety fallback
    naive_tril<<<dim3(16, NN), 256, 0, stream>>>(A, B, C);
    return;
  }

  u16* Ab = (u16*)d_ws;
  u16* Bt = Ab + (long)NN * NN;
  u16* P = (u16*)((char*)d_ws + opbytes);

  hipFuncSetAttribute((const void*)gemm_tril,
                      hipFuncAttributeMaxDynamicSharedMemorySize, 131072);

  convert_fused<<<3200, 256, 0, stream>>>(A, B, Ab, Bt);
  gemm_tril<<<376, 512, 131072, stream>>>(Ab, Bt, C, P);
  reduce_partials<<<544, 256, 0, stream>>>(C, P);
}

// Round 19
// 78.253 us; speedup vs baseline: 2.0905x; 2.0905x over previous
//
#include <hip/hip_runtime.h>
#include <hip/hip_bf16.h>

#define NN 4096

typedef unsigned short u16;
typedef __attribute__((ext_vector_type(8))) short bf16x8;
typedef __attribute__((ext_vector_type(4))) float f32x4;

// fp32 -> bf16 round-to-nearest-even
static __device__ __forceinline__ u16 f2bf(float x) {
  unsigned u = __float_as_uint(x);
  u += 0x7fff + ((u >> 16) & 1);
  return (u16)(u >> 16);
}
static __device__ __forceinline__ float bf2f(u16 h) {
  return __uint_as_float((unsigned)h << 16);
}

// async global->LDS, 16B per lane; LDS dest = wave-uniform base + lane*16
static __device__ __forceinline__ void gload_lds16(const void* g, void* l) {
  __builtin_amdgcn_global_load_lds(
      (const __attribute__((address_space(1))) void*)g,
      (__attribute__((address_space(3))) void*)l, 16, 0, 0);
}

// F(M) = sum_{j=0}^{M-1} floor(j/2^lg)
static __device__ __forceinline__ int Fpre(int M, int lg) {
  if (M <= 0) return 0;
  const int q = (M - 1) >> lg, r = (M - 1) & ((1 << lg) - 1);
  return ((q * (q - 1)) << (lg - 1)) + q * (r + 1);
}

// ---------------------------------------------------------------------------
// Pass 1 (fused, grid 3200): R16 structure; A-path now uses 16B stores
// (uint4 of 8 bf16) with all 16 loads batched in flight (was 8B ushort4;
// convert measured latency-bound: 2.5 TB/s, VALUBusy 5.7%).
// ---------------------------------------------------------------------------
__global__ __launch_bounds__(256) void convert_fused(
    const float* __restrict__ A, const float* __restrict__ B,
    u16* __restrict__ Ab, u16* __restrict__ Bt) {
  __shared__ float t[64][65];
  const int blk = blockIdx.x;
  const int tid = threadIdx.x;

  if (blk < 1024) {  // ---- A path: 128x128 block (bi,kb) ----
    const int kb = blk & 31, bi = blk >> 5;
    if (kb > bi) {
      if (kb == bi + 1 && !(bi & 1)) {  // super-diagonal Ab: real zeros
        const uint4 zz = {0u, 0u, 0u, 0u};
        const int r0 = tid >> 4;
        const int cq = (tid & 15) * 8;
#pragma unroll
        for (int h = 0; h < 8; ++h)
          *(uint4*)&Ab[(long)(bi * 128 + h * 16 + r0) * NN + kb * 128 + cq] =
              zz;
      }
      return;
    }
    const int r0 = tid >> 4;        // 0..15
    const int cq = (tid & 15) * 8;  // 8 cols per thread
    const bool diag = (kb == bi);
    float4 v0[8], v1[8];
#pragma unroll
    for (int h = 0; h < 8; ++h) {  // 16 loads in flight
      const float* src =
          &A[(long)(bi * 128 + h * 16 + r0) * NN + kb * 128 + cq];
      v0[h] = *(const float4*)src;
      v1[h] = *(const float4*)(src + 4);
    }
#pragma unroll
    for (int h = 0; h < 8; ++h) {
      const int row = h * 16 + r0;
      union { u16 e[8]; uint4 v; } o;
      o.e[0] = f2bf(v0[h].x); o.e[1] = f2bf(v0[h].y);
      o.e[2] = f2bf(v0[h].z); o.e[3] = f2bf(v0[h].w);
      o.e[4] = f2bf(v1[h].x); o.e[5] = f2bf(v1[h].y);
      o.e[6] = f2bf(v1[h].z); o.e[7] = f2bf(v1[h].w);
      if (diag) {
        const int i = bi * 128 + row, k = kb * 128 + cq;
#pragma unroll
        for (int e = 0; e < 8; ++e)
          if (k + e > i) o.e[e] = 0;
      }
      *(uint4*)&Ab[(long)(bi * 128 + row) * NN + kb * 128 + cq] = o.v;
    }
    return;
  }

  if (blk >= 3136) {  // ---- sub-diagonal Bt zero blocks ----
    const int idx = blk - 3136;  // 0..63
    const int q = idx >> 2;
    const int n0 = (2 * (2 * q + 1) + (idx & 1)) * 64;
    const int k0 = (2 * (2 * q) + ((idx >> 1) & 1)) * 64;
    const int n = tid >> 3;
    const int kc = (tid & 7) * 8;
    const uint4 z = {0u, 0u, 0u, 0u};
#pragma unroll
    for (int p = 0; p < 2; ++p)
      *(uint4*)&Bt[(long)(n0 + n + p * 32) * NN + k0 + kc] = z;
    return;
  }

  // ---- B path: pair-decoded 64x64 transpose tile ----
  const int t4 = blk - 1024;  // 0..2111
  int prem = t4 >> 2, N = 0;
  while (prem >= 32 - N) { prem -= 32 - N; ++N; }
  const int K = N + prem;  // N <= K
  const int sub = t4 & 3;
  const int n0 = (2 * N + (sub & 1)) * 64;
  const int k0 = (2 * K + (sub >> 1)) * 64;

  if (n0 > k0 + 63) {  // fully above diagonal -> zeros
    const int n = tid >> 3;
    const int kc = (tid & 7) * 8;
    const uint4 z = {0u, 0u, 0u, 0u};
#pragma unroll
    for (int p = 0; p < 2; ++p)
      *(uint4*)&Bt[(long)(n0 + n + p * 32) * NN + k0 + kc] = z;
    return;
  }

  float4 w[4];
#pragma unroll
  for (int p = 0; p < 4; ++p) {  // 4 loads in flight (ILP)
    const int r = (tid >> 4) + p * 16;
    w[p] = *(const float4*)&B[(long)(k0 + r) * NN + n0 + (tid & 15) * 4];
  }
#pragma unroll
  for (int p = 0; p < 4; ++p) {
    const int r = (tid >> 4) + p * 16;
    const int c = (tid & 15) * 4;
    const int kg = k0 + r;
    t[r][c + 0] = (n0 + c + 0 <= kg) ? w[p].x : 0.f;
    t[r][c + 1] = (n0 + c + 1 <= kg) ? w[p].y : 0.f;
    t[r][c + 2] = (n0 + c + 2 <= kg) ? w[p].z : 0.f;
    t[r][c + 3] = (n0 + c + 3 <= kg) ? w[p].w : 0.f;
  }
  __syncthreads();

#pragma unroll
  for (int p = 0; p < 2; ++p) {
    const int n = (tid >> 3) + p * 32;
    const int kc = (tid & 7) * 8;
    union { u16 h[8]; uint4 v; } pk;
#pragma unroll
    for (int j = 0; j < 8; ++j) pk.h[j] = f2bf(t[kc + j][n]);
    *(uint4*)&Bt[(long)(n0 + n) * NN + k0 + kc] = pk.v;
  }
}

// ---------------------------------------------------------------------------
// Pass 2: R16 gemm with two tweaks: (a) stage parts issue at phases 0-1
// (last loads get ~1.8us flight before next step's vmcnt(0)); (b) zero
// tail-tile writes NONTEMPORAL (no consumer -> keep 31 MB out of L3 so
// operands stay resident, cutting compute-path FETCH).
// ---------------------------------------------------------------------------
__global__ __launch_bounds__(512, 2) void gemm_tril(
    const u16* __restrict__ Ab, const u16* __restrict__ Bt,
    float* __restrict__ C, u16* __restrict__ P, int lg, int nitems) {
  extern __shared__ u16 lds[];  // [2][16384] A | [2][16384] B = 128 KB
  u16* AsB = lds;
  u16* BsB = lds + 32768;

  const int tid = threadIdx.x;

  if ((int)blockIdx.x >= nitems) {  // ---- zero a strictly-upper 256-tile ----
    int zi = blockIdx.x - nitems;   // 0..119
    int bi = 0;
    for (; bi < 15; ++bi) {
      const int u = 15 - bi;
      if (zi < u) break;
      zi -= u;
    }
    const int bj = bi + 1 + zi;
    const f32x4 z = {0.f, 0.f, 0.f, 0.f};
#pragma unroll
    for (int p = 0; p < 32; ++p) {
      const int idx = p * 512 + tid;
      const int row = idx >> 6;
      const int col = (idx & 63) * 4;
      __builtin_nontemporal_store(
          z, (f32x4*)&C[(long)(bi * 256 + row) * NN + bj * 256 + col]);
    }
    return;
  }

  const int lane = tid & 63;
  const int wid = tid >> 6;  // 0..7
  const int wm = wid >> 2;   // 0..1 (128-row half)
  const int wn = wid & 3;    // 0..3 (64-col block)
  const int sm = lane >> 3;
  const int sks = ((lane & 7) ^ sm) * 8;  // pre-swizzled source col (u16)
  const int rsel = lane & 7;

  // ---- decode blockIdx.x -> (bi, bj, chunk); 256-rows longest-K-first ----
  int rem = blockIdx.x, bi = 15, slabpre = 0;
  for (int s = 0; s < 16; ++s) {
    bi = 15 - s;
    const int fp = Fpre(bi + 1, lg);
    const int g = (bi + 1) + fp;
    if (rem < g) break;
    rem -= g;
    slabpre += fp;
  }
  int bj = 0;
  for (;;) {
    const int c = ((bi - bj) >> lg) + 1;  // chunks of tile (bi,bj)
    if (rem < c) break;
    rem -= c;
    ++bj;
  }
  const int chunk = rem;
  const int L64 = 4 * (bi - bj + 1);
  const int H64 = 4 << lg;
  const int start = chunk * H64;
  const int nk = min(H64, L64 - start);
  const int rA = bi * 256;
  const int rB = bj * 256;
  const long kbase = (long)bj * 256 + (long)start * 64;

  f32x4 acc[8][4];
#pragma unroll
  for (int i = 0; i < 8; ++i)
#pragma unroll
    for (int j = 0; j < 4; ++j) acc[i][j] = (f32x4){0.f, 0.f, 0.f, 0.f};

  // stage part c (of 4) of K64-step kt into buffer b: 2 gload_lds16
#define STAGE_PART(kt, b, c)                                               \
  do {                                                                     \
    const long k0 = kbase + (long)(kt)*64;                                 \
    const int ch = wid * 4 + (c);                                          \
    gload_lds16(Ab + ((long)(rA + ch * 8 + sm) * NN + k0 + sks),           \
                AsB + (b)*16384 + ch * 512);                               \
    gload_lds16(Bt + ((long)(rB + ch * 8 + sm) * NN + k0 + sks),           \
                BsB + (b)*16384 + ch * 512);                               \
  } while (0)

#pragma unroll
  for (int c = 0; c < 4; ++c) STAGE_PART(0, 0, c);

  for (int kt = 0; kt < nk; ++kt) {
    const int cur = kt & 1;
    asm volatile("s_waitcnt vmcnt(0)" ::: "memory");  // own stage landed
    __builtin_amdgcn_s_barrier();                     // all waves' stage done
    __builtin_amdgcn_sched_barrier(0);                // no read hoists above

    const u16* As = AsB + cur * 16384;
    const u16* Bs = BsB + cur * 16384;
    const bool pf = (kt + 1 < nk);

    // B fragments (whole step) + A fragments for phase 0
    bf16x8 bb[4][2];
#pragma unroll
    for (int n4 = 0; n4 < 4; ++n4)
#pragma unroll
      for (int kk = 0; kk < 2; ++kk) {
        const int fr = wn * 64 + n4 * 16 + (lane & 15);
        const int slot = ((kk * 4 + (lane >> 4)) ^ rsel) * 8;
        bb[n4][kk] = *(const bf16x8*)&Bs[fr * 64 + slot];
      }
    bf16x8 aa[2][2][2];  // [phase&1][mm][kk]
#pragma unroll
    for (int mm = 0; mm < 2; ++mm)
#pragma unroll
      for (int kk = 0; kk < 2; ++kk) {
        const int fr = wm * 128 + mm * 16 + (lane & 15);
        const int slot = ((kk * 4 + (lane >> 4)) ^ rsel) * 8;
        aa[0][mm][kk] = *(const bf16x8*)&As[fr * 64 + slot];
      }

#pragma unroll
    for (int p = 0; p < 4; ++p) {
      if (pf && p < 2) {  // stage early (phases 0-1), 2 parts per phase
        STAGE_PART(kt + 1, cur ^ 1, 2 * p);
        STAGE_PART(kt + 1, cur ^ 1, 2 * p + 1);
      }
      if (p < 3) {  // prefetch next phase's A fragments
#pragma unroll
        for (int mm = 0; mm < 2; ++mm)
#pragma unroll
          for (int kk = 0; kk < 2; ++kk) {
            const int fr = wm * 128 + (2 * (p + 1) + mm) * 16 + (lane & 15);
            const int slot = ((kk * 4 + (lane >> 4)) ^ rsel) * 8;
            aa[(p + 1) & 1][mm][kk] = *(const bf16x8*)&As[fr * 64 + slot];
          }
        asm volatile("s_waitcnt lgkmcnt(4)" ::: "memory");  // cur frags done
      } else {
        asm volatile("s_waitcnt lgkmcnt(0)" ::: "memory");
      }
      __builtin_amdgcn_sched_barrier(0);  // rule #18: no MFMA hoist past wait
      __builtin_amdgcn_s_setprio(1);
#pragma unroll
      for (int kk = 0; kk < 2; ++kk)
#pragma unroll
        for (int mm = 0; mm < 2; ++mm)
#pragma unroll
          for (int n4 = 0; n4 < 4; ++n4)
            acc[2 * p + mm][n4] = __builtin_amdgcn_mfma_f32_16x16x32_bf16(
                aa[p & 1][mm][kk], bb[n4][kk], acc[2 * p + mm][n4], 0, 0, 0);
      __builtin_amdgcn_s_setprio(0);
    }
  }
#undef STAGE_PART

  // ---- epilogue: C/D layout col=lane&15, row=(lane>>4)*4+r ----
  const int lrow = wm * 128 + (lane >> 4) * 4;
  const int lcol = wn * 64 + (lane & 15);
  if (chunk == 0) {
    const bool diag = (bi == bj);
#pragma unroll
    for (int m4 = 0; m4 < 8; ++m4)
#pragma unroll
      for (int n4 = 0; n4 < 4; ++n4)
#pragma unroll
        for (int r = 0; r < 4; ++r) {
          const int gi = rA + lrow + m4 * 16 + r;
          const int gj = rB + lcol + n4 * 16;
          float v = acc[m4][n4][r];
          if (diag && gj > gi) v = 0.f;
          C[(long)gi * NN + gj] = v;
        }
  } else {
    const int slabidx =
        slabpre + (Fpre(bi + 1, lg) - Fpre(bi - bj + 1, lg)) + (chunk - 1);
    u16* slab = P + (long)slabidx * 65536;  // 256x256 bf16 = 128 KB
#pragma unroll
    for (int m4 = 0; m4 < 8; ++m4)
#pragma unroll
      for (int n4 = 0; n4 < 4; ++n4)
#pragma unroll
        for (int r = 0; r < 4; ++r)
          slab[(lrow + m4 * 16 + r) * 256 + lcol + n4 * 16] =
              f2bf(acc[m4][n4][r]);
  }
}

// ---------------------------------------------------------------------------
// Pass 3: add bf16 partial slabs into C. Multi-chunk tiles only
// (bi-bj >= 2^lg), 4 row-stripes per tile.
// ---------------------------------------------------------------------------
__global__ __launch_bounds__(256) void reduce_partials(
    float* __restrict__ C, const u16* __restrict__ P, int lg) {
  const int G = 1 << lg;
  const int tb = blockIdx.x >> 2;
  const int stripe = blockIdx.x & 3;
  int rem = tb, bi = 15, slabpre = 0;
  for (int s = 0; s < 16; ++s) {
    bi = 15 - s;
    const int g = (bi + 1 - G > 0) ? bi + 1 - G : 0;
    if (rem < g) break;
    rem -= g;
    slabpre += Fpre(bi + 1, lg);
  }
  const int bj = rem;  // bj <= bi-G -> nch >= 2
  const int nch = ((bi - bj) >> lg) + 1;
  const int slaboff = slabpre + (Fpre(bi + 1, lg) - Fpre(bi - bj + 1, lg));

  const int tid = threadIdx.x;
#pragma unroll
  for (int p = 0; p < 16; ++p) {
    const int idx = p * 256 + tid;  // 4096 float4 per 64-row stripe
    const int row = stripe * 64 + (idx >> 6);
    const int col = (idx & 63) * 4;
    const long coff = (long)(bi * 256 + row) * NN + bj * 256 + col;
    float4 acc = *(const float4*)&C[coff];
    for (int e = 0; e < nch - 1; ++e) {
      const ushort4 q =
          *(const ushort4*)&P[(long)(slaboff + e) * 65536 + row * 256 + col];
      acc.x += bf2f(q.x); acc.y += bf2f(q.y);
      acc.z += bf2f(q.z); acc.w += bf2f(q.w);
    }
    *(float4*)&C[coff] = acc;
  }
}

// ---------------------------------------------------------------------------
// Fallback (ws too small): naive fp32.
// ---------------------------------------------------------------------------
__global__ void naive_tril(const float* __restrict__ A,
                           const float* __restrict__ B, float* __restrict__ C) {
  const int j = blockIdx.x * 256 + threadIdx.x;
  const int i = blockIdx.y;
  float s = 0.f;
  for (int k = j; k <= i; ++k) s += A[(long)i * NN + k] * B[(long)k * NN + j];
  C[(long)i * NN + j] = s;
}

extern "C" void kernel_launch(void* const* d_in, const int* in_sizes, int n_in,
                              void* d_out, int out_size, void* d_ws,
                              size_t ws_size, hipStream_t stream) {
  const float* A = (const float*)d_in[0];
  const float* B = (const float*)d_in[1];
  float* C = (float*)d_out;

  const size_t opbytes = (size_t)2 * NN * NN * sizeof(u16);  // 64 MB operands
  const size_t slab = 131072;  // 256x256 bf16
  const size_t need2 = opbytes + 124 * slab;  // 79.5 MB (lg=2, proven best)
  const size_t need3 = opbytes + 36 * slab;

  if (ws_size < opbytes) {
    naive_tril<<<dim3(16, NN), 256, 0, stream>>>(A, B, C);
    return;
  }

  int lg, nitems, nred;
  if (ws_size >= need2)      { lg = 2; nitems = 260; nred = 78; }
  else if (ws_size >= need3) { lg = 3; nitems = 172; nred = 36; }
  else                       { lg = 4; nitems = 136; nred = 0; }

  u16* Ab = (u16*)d_ws;
  u16* Bt = Ab + (long)NN * NN;
  u16* P = (u16*)((char*)d_ws + opbytes);

  hipFuncSetAttribute((const void*)gemm_tril,
                      hipFuncAttributeMaxDynamicSharedMemorySize, 131072);

  convert_fused<<<3200, 256, 0, stream>>>(A, B, Ab, Bt);
  gemm_tril<<<nitems + 120, 512, 131072, stream>>>(Ab, Bt, C, P, lg, nitems);
  if (nred > 0) reduce_partials<<<nred * 4, 256, 0, stream>>>(C, P, lg);
}

// Round 20
// 77.761 us; speedup vs baseline: 2.1037x; 1.0063x over previous
//
#include <hip/hip_runtime.h>
#include <hip/hip_bf16.h>

#define NN 4096

typedef unsigned short u16;
typedef __attribute__((ext_vector_type(8))) short bf16x8;
typedef __attribute__((ext_vector_type(4))) float f32x4;

// fp32 -> bf16 round-to-nearest-even
static __device__ __forceinline__ u16 f2bf(float x) {
  unsigned u = __float_as_uint(x);
  u += 0x7fff + ((u >> 16) & 1);
  return (u16)(u >> 16);
}
static __device__ __forceinline__ float bf2f(u16 h) {
  return __uint_as_float((unsigned)h << 16);
}

// async global->LDS, 16B per lane; LDS dest = wave-uniform base + lane*16
static __device__ __forceinline__ void gload_lds16(const void* g, void* l) {
  __builtin_amdgcn_global_load_lds(
      (const __attribute__((address_space(1))) void*)g,
      (__attribute__((address_space(3))) void*)l, 16, 0, 0);
}

// F(M) = sum_{j=0}^{M-1} floor(j/2^lg)
static __device__ __forceinline__ int Fpre(int M, int lg) {
  if (M <= 0) return 0;
  const int q = (M - 1) >> lg, r = (M - 1) & ((1 << lg) - 1);
  return ((q * (q - 1)) << (lg - 1)) + q * (r + 1);
}

// ---------------------------------------------------------------------------
// Pass 1 (fused, grid 2144): convert was issue/latency-bound (2.5 TB/s,
// VALUBusy 5.7%) -- B-path restructured to 64k x 128n tiles: 2x work/block,
// 8 loads in flight (was 4), half the blocks. A-path = R19 (16B stores,
// 16 loads in flight).
//  [0,1024):     A path: tril bf16 convert (kb<=bi); kb==bi+1 & bi even:
//                zero super-diagonal Ab block.
//  [1024,2080):  B -> Bt transpose, 528 pairs x 2 k-subtiles.
//  [2080,2144):  zero sub-diagonal Bt 128-blocks.
// ---------------------------------------------------------------------------
__global__ __launch_bounds__(256) void convert_fused(
    const float* __restrict__ A, const float* __restrict__ B,
    u16* __restrict__ Ab, u16* __restrict__ Bt) {
  __shared__ float t[64][129];  // 33 KB
  const int blk = blockIdx.x;
  const int tid = threadIdx.x;

  if (blk < 1024) {  // ---- A path: 128x128 block (bi,kb) ----
    const int kb = blk & 31, bi = blk >> 5;
    if (kb > bi) {
      if (kb == bi + 1 && !(bi & 1)) {  // super-diagonal Ab: real zeros
        const uint4 zz = {0u, 0u, 0u, 0u};
        const int r0 = tid >> 4;
        const int cq = (tid & 15) * 8;
#pragma unroll
        for (int h = 0; h < 8; ++h)
          *(uint4*)&Ab[(long)(bi * 128 + h * 16 + r0) * NN + kb * 128 + cq] =
              zz;
      }
      return;
    }
    const int r0 = tid >> 4;        // 0..15
    const int cq = (tid & 15) * 8;  // 8 cols per thread
    const bool diag = (kb == bi);
    float4 v0[8], v1[8];
#pragma unroll
    for (int h = 0; h < 8; ++h) {  // 16 loads in flight
      const float* src =
          &A[(long)(bi * 128 + h * 16 + r0) * NN + kb * 128 + cq];
      v0[h] = *(const float4*)src;
      v1[h] = *(const float4*)(src + 4);
    }
#pragma unroll
    for (int h = 0; h < 8; ++h) {
      const int row = h * 16 + r0;
      union { u16 e[8]; uint4 v; } o;
      o.e[0] = f2bf(v0[h].x); o.e[1] = f2bf(v0[h].y);
      o.e[2] = f2bf(v0[h].z); o.e[3] = f2bf(v0[h].w);
      o.e[4] = f2bf(v1[h].x); o.e[5] = f2bf(v1[h].y);
      o.e[6] = f2bf(v1[h].z); o.e[7] = f2bf(v1[h].w);
      if (diag) {
        const int i = bi * 128 + row, k = kb * 128 + cq;
#pragma unroll
        for (int e = 0; e < 8; ++e)
          if (k + e > i) o.e[e] = 0;
      }
      *(uint4*)&Ab[(long)(bi * 128 + row) * NN + kb * 128 + cq] = o.v;
    }
    return;
  }

  if (blk >= 2080) {  // ---- sub-diagonal Bt zero blocks ----
    const int idx = blk - 2080;  // 0..63
    const int q = idx >> 2;
    const int n0 = (2 * (2 * q + 1) + (idx & 1)) * 64;
    const int k0 = (2 * (2 * q) + ((idx >> 1) & 1)) * 64;
    const int n = tid >> 3;
    const int kc = (tid & 7) * 8;
    const uint4 z = {0u, 0u, 0u, 0u};
#pragma unroll
    for (int p = 0; p < 2; ++p)
      *(uint4*)&Bt[(long)(n0 + n + p * 32) * NN + k0 + kc] = z;
    return;
  }

  // ---- B path: 64k x 128n transpose tile over needed (N<=K) 128-pairs ----
  const int t2 = blk - 1024;  // 0..1055
  int prem = t2 >> 1, N = 0;  // pair index 0..527
  while (prem >= 32 - N) { prem -= 32 - N; ++N; }
  const int K = N + prem;     // N <= K
  const int n0 = N * 128;
  const int k0 = K * 128 + (t2 & 1) * 64;

  float4 w[8];
#pragma unroll
  for (int p = 0; p < 8; ++p) {  // 8 loads in flight (ILP)
    const int idx = p * 256 + tid;
    const int r = idx >> 5;          // 0..63 (k row)
    const int c4 = (idx & 31) * 4;   // 0..124 (n col quad)
    w[p] = *(const float4*)&B[(long)(k0 + r) * NN + n0 + c4];
  }
#pragma unroll
  for (int p = 0; p < 8; ++p) {
    const int idx = p * 256 + tid;
    const int r = idx >> 5;
    const int c4 = (idx & 31) * 4;
    const int kg = k0 + r;
    t[r][c4 + 0] = (n0 + c4 + 0 <= kg) ? w[p].x : 0.f;
    t[r][c4 + 1] = (n0 + c4 + 1 <= kg) ? w[p].y : 0.f;
    t[r][c4 + 2] = (n0 + c4 + 2 <= kg) ? w[p].z : 0.f;
    t[r][c4 + 3] = (n0 + c4 + 3 <= kg) ? w[p].w : 0.f;
  }
  __syncthreads();

#pragma unroll
  for (int q = 0; q < 4; ++q) {
    const int idx = q * 256 + tid;
    const int n = idx >> 3;         // 0..127
    const int kc = (idx & 7) * 8;   // 0..56
    union { u16 h[8]; uint4 v; } pk;
#pragma unroll
    for (int j = 0; j < 8; ++j) pk.h[j] = f2bf(t[kc + j][n]);
    *(uint4*)&Bt[(long)(n0 + n) * NN + k0 + kc] = pk.v;
  }
}

// ---------------------------------------------------------------------------
// Pass 2: R19 gemm (unchanged -- proven 39.2us): lean 1-barrier step,
// lgkmcnt(4) phase pipeline, stage at phases 0-1, T2 swizzle, bf16 slabs,
// nontemporal zero tail tiles.
// ---------------------------------------------------------------------------
__global__ __launch_bounds__(512, 2) void gemm_tril(
    const u16* __restrict__ Ab, const u16* __restrict__ Bt,
    float* __restrict__ C, u16* __restrict__ P, int lg, int nitems) {
  extern __shared__ u16 lds[];  // [2][16384] A | [2][16384] B = 128 KB
  u16* AsB = lds;
  u16* BsB = lds + 32768;

  const int tid = threadIdx.x;

  if ((int)blockIdx.x >= nitems) {  // ---- zero a strictly-upper 256-tile ----
    int zi = blockIdx.x - nitems;   // 0..119
    int bi = 0;
    for (; bi < 15; ++bi) {
      const int u = 15 - bi;
      if (zi < u) break;
      zi -= u;
    }
    const int bj = bi + 1 + zi;
    const f32x4 z = {0.f, 0.f, 0.f, 0.f};
#pragma unroll
    for (int p = 0; p < 32; ++p) {
      const int idx = p * 512 + tid;
      const int row = idx >> 6;
      const int col = (idx & 63) * 4;
      __builtin_nontemporal_store(
          z, (f32x4*)&C[(long)(bi * 256 + row) * NN + bj * 256 + col]);
    }
    return;
  }

  const int lane = tid & 63;
  const int wid = tid >> 6;  // 0..7
  const int wm = wid >> 2;   // 0..1 (128-row half)
  const int wn = wid & 3;    // 0..3 (64-col block)
  const int sm = lane >> 3;
  const int sks = ((lane & 7) ^ sm) * 8;  // pre-swizzled source col (u16)
  const int rsel = lane & 7;

  // ---- decode blockIdx.x -> (bi, bj, chunk); 256-rows longest-K-first ----
  int rem = blockIdx.x, bi = 15, slabpre = 0;
  for (int s = 0; s < 16; ++s) {
    bi = 15 - s;
    const int fp = Fpre(bi + 1, lg);
    const int g = (bi + 1) + fp;
    if (rem < g) break;
    rem -= g;
    slabpre += fp;
  }
  int bj = 0;
  for (;;) {
    const int c = ((bi - bj) >> lg) + 1;  // chunks of tile (bi,bj)
    if (rem < c) break;
    rem -= c;
    ++bj;
  }
  const int chunk = rem;
  const int L64 = 4 * (bi - bj + 1);
  const int H64 = 4 << lg;
  const int start = chunk * H64;
  const int nk = min(H64, L64 - start);
  const int rA = bi * 256;
  const int rB = bj * 256;
  const long kbase = (long)bj * 256 + (long)start * 64;

  f32x4 acc[8][4];
#pragma unroll
  for (int i = 0; i < 8; ++i)
#pragma unroll
    for (int j = 0; j < 4; ++j) acc[i][j] = (f32x4){0.f, 0.f, 0.f, 0.f};

  // stage part c (of 4) of K64-step kt into buffer b: 2 gload_lds16
#define STAGE_PART(kt, b, c)                                               \
  do {                                                                     \
    const long k0 = kbase + (long)(kt)*64;                                 \
    const int ch = wid * 4 + (c);                                          \
    gload_lds16(Ab + ((long)(rA + ch * 8 + sm) * NN + k0 + sks),           \
                AsB + (b)*16384 + ch * 512);                               \
    gload_lds16(Bt + ((long)(rB + ch * 8 + sm) * NN + k0 + sks),           \
                BsB + (b)*16384 + ch * 512);                               \
  } while (0)

#pragma unroll
  for (int c = 0; c < 4; ++c) STAGE_PART(0, 0, c);

  for (int kt = 0; kt < nk; ++kt) {
    const int cur = kt & 1;
    asm volatile("s_waitcnt vmcnt(0)" ::: "memory");  // own stage landed
    __builtin_amdgcn_s_barrier();                     // all waves' stage done
    __builtin_amdgcn_sched_barrier(0);                // no read hoists above

    const u16* As = AsB + cur * 16384;
    const u16* Bs = BsB + cur * 16384;
    const bool pf = (kt + 1 < nk);

    // B fragments (whole step) + A fragments for phase 0
    bf16x8 bb[4][2];
#pragma unroll
    for (int n4 = 0; n4 < 4; ++n4)
#pragma unroll
      for (int kk = 0; kk < 2; ++kk) {
        const int fr = wn * 64 + n4 * 16 + (lane & 15);
        const int slot = ((kk * 4 + (lane >> 4)) ^ rsel) * 8;
        bb[n4][kk] = *(const bf16x8*)&Bs[fr * 64 + slot];
      }
    bf16x8 aa[2][2][2];  // [phase&1][mm][kk]
#pragma unroll
    for (int mm = 0; mm < 2; ++mm)
#pragma unroll
      for (int kk = 0; kk < 2; ++kk) {
        const int fr = wm * 128 + mm * 16 + (lane & 15);
        const int slot = ((kk * 4 + (lane >> 4)) ^ rsel) * 8;
        aa[0][mm][kk] = *(const bf16x8*)&As[fr * 64 + slot];
      }

#pragma unroll
    for (int p = 0; p < 4; ++p) {
      if (pf && p < 2) {  // stage early (phases 0-1), 2 parts per phase
        STAGE_PART(kt + 1, cur ^ 1, 2 * p);
        STAGE_PART(kt + 1, cur ^ 1, 2 * p + 1);
      }
      if (p < 3) {  // prefetch next phase's A fragments
#pragma unroll
        for (int mm = 0; mm < 2; ++mm)
#pragma unroll
          for (int kk = 0; kk < 2; ++kk) {
            const int fr = wm * 128 + (2 * (p + 1) + mm) * 16 + (lane & 15);
            const int slot = ((kk * 4 + (lane >> 4)) ^ rsel) * 8;
            aa[(p + 1) & 1][mm][kk] = *(const bf16x8*)&As[fr * 64 + slot];
          }
        asm volatile("s_waitcnt lgkmcnt(4)" ::: "memory");  // cur frags done
      } else {
        asm volatile("s_waitcnt lgkmcnt(0)" ::: "memory");
      }
      __builtin_amdgcn_sched_barrier(0);  // rule #18: no MFMA hoist past wait
      __builtin_amdgcn_s_setprio(1);
#pragma unroll
      for (int kk = 0; kk < 2; ++kk)
#pragma unroll
        for (int mm = 0; mm < 2; ++mm)
#pragma unroll
          for (int n4 = 0; n4 < 4; ++n4)
            acc[2 * p + mm][n4] = __builtin_amdgcn_mfma_f32_16x16x32_bf16(
                aa[p & 1][mm][kk], bb[n4][kk], acc[2 * p + mm][n4], 0, 0, 0);
      __builtin_amdgcn_s_setprio(0);
    }
  }
#undef STAGE_PART

  // ---- epilogue: C/D layout col=lane&15, row=(lane>>4)*4+r ----
  const int lrow = wm * 128 + (lane >> 4) * 4;
  const int lcol = wn * 64 + (lane & 15);
  if (chunk == 0) {
    const bool diag = (bi == bj);
#pragma unroll
    for (int m4 = 0; m4 < 8; ++m4)
#pragma unroll
      for (int n4 = 0; n4 < 4; ++n4)
#pragma unroll
        for (int r = 0; r < 4; ++r) {
          const int gi = rA + lrow + m4 * 16 + r;
          const int gj = rB + lcol + n4 * 16;
          float v = acc[m4][n4][r];
          if (diag && gj > gi) v = 0.f;
          C[(long)gi * NN + gj] = v;
        }
  } else {
    const int slabidx =
        slabpre + (Fpre(bi + 1, lg) - Fpre(bi - bj + 1, lg)) + (chunk - 1);
    u16* slab = P + (long)slabidx * 65536;  // 256x256 bf16 = 128 KB
#pragma unroll
    for (int m4 = 0; m4 < 8; ++m4)
#pragma unroll
      for (int n4 = 0; n4 < 4; ++n4)
#pragma unroll
        for (int r = 0; r < 4; ++r)
          slab[(lrow + m4 * 16 + r) * 256 + lcol + n4 * 16] =
              f2bf(acc[m4][n4][r]);
  }
}

// ---------------------------------------------------------------------------
// Pass 3: add bf16 partial slabs into C. Multi-chunk tiles only
// (bi-bj >= 2^lg), 4 row-stripes per tile.
// ---------------------------------------------------------------------------
__global__ __launch_bounds__(256) void reduce_partials(
    float* __restrict__ C, const u16* __restrict__ P, int lg) {
  const int G = 1 << lg;
  const int tb = blockIdx.x >> 2;
  const int stripe = blockIdx.x & 3;
  int rem = tb, bi = 15, slabpre = 0;
  for (int s = 0; s < 16; ++s) {
    bi = 15 - s;
    const int g = (bi + 1 - G > 0) ? bi + 1 - G : 0;
    if (rem < g) break;
    rem -= g;
    slabpre += Fpre(bi + 1, lg);
  }
  const int bj = rem;  // bj <= bi-G -> nch >= 2
  const int nch = ((bi - bj) >> lg) + 1;
  const int slaboff = slabpre + (Fpre(bi + 1, lg) - Fpre(bi - bj + 1, lg));

  const int tid = threadIdx.x;
#pragma unroll
  for (int p = 0; p < 16; ++p) {
    const int idx = p * 256 + tid;  // 4096 float4 per 64-row stripe
    const int row = stripe * 64 + (idx >> 6);
    const int col = (idx & 63) * 4;
    const long coff = (long)(bi * 256 + row) * NN + bj * 256 + col;
    float4 acc = *(const float4*)&C[coff];
    for (int e = 0; e < nch - 1; ++e) {
      const ushort4 q =
          *(const ushort4*)&P[(long)(slaboff + e) * 65536 + row * 256 + col];
      acc.x += bf2f(q.x); acc.y += bf2f(q.y);
      acc.z += bf2f(q.z); acc.w += bf2f(q.w);
    }
    *(float4*)&C[coff] = acc;
  }
}

// ---------------------------------------------------------------------------
// Fallback (ws too small): naive fp32.
// ---------------------------------------------------------------------------
__global__ void naive_tril(const float* __restrict__ A,
                           const float* __restrict__ B, float* __restrict__ C) {
  const int j = blockIdx.x * 256 + threadIdx.x;
  const int i = blockIdx.y;
  float s = 0.f;
  for (int k = j; k <= i; ++k) s += A[(long)i * NN + k] * B[(long)k * NN + j];
  C[(long)i * NN + j] = s;
}

extern "C" void kernel_launch(void* const* d_in, const int* in_sizes, int n_in,
                              void* d_out, int out_size, void* d_ws,
                              size_t ws_size, hipStream_t stream) {
  const float* A = (const float*)d_in[0];
  const float* B = (const float*)d_in[1];
  float* C = (float*)d_out;

  const size_t opbytes = (size_t)2 * NN * NN * sizeof(u16);  // 64 MB operands
  const size_t slab = 131072;  // 256x256 bf16
  const size_t need2 = opbytes + 124 * slab;  // 79.5 MB (lg=2, proven best)
  const size_t need3 = opbytes + 36 * slab;

  if (ws_size < opbytes) {
    naive_tril<<<dim3(16, NN), 256, 0, stream>>>(A, B, C);
    return;
  }

  int lg, nitems, nred;
  if (ws_size >= need2)      { lg = 2; nitems = 260; nred = 78; }
  else if (ws_size >= need3) { lg = 3; nitems = 172; nred = 36; }
  else                       { lg = 4; nitems = 136; nred = 0; }

  u16* Ab = (u16*)d_ws;
  u16* Bt = Ab + (long)NN * NN;
  u16* P = (u16*)((char*)d_ws + opbytes);

  hipFuncSetAttribute((const void*)gemm_tril,
                      hipFuncAttributeMaxDynamicSharedMemorySize, 131072);

  convert_fused<<<2144, 256, 0, stream>>>(A, B, Ab, Bt);
  gemm_tril<<<nitems + 120, 512, 131072, stream>>>(Ab, Bt, C, P, lg, nitems);
  if (nred > 0) reduce_partials<<<nred * 4, 256, 0, stream>>>(C, P, lg);
}